// Round 1
// baseline (39.869 us; speedup 1.0000x reference)
//
#include <hip/hip_runtime.h>

#define GRIDS 7
#define NCELL 49
#define NFEAT 25
#define CELLSZ 1225   // 49*25 floats per batch
#define BPB 8         // batches per block (8*4900 bytes => float4-aligned per block)
#define MAXBOX 16

// Per-element loss:
//   f in [0,2): 5*obj*((xo|yo) - p)^2
//   f in [2,4): 5*obj*(sqrt(w|h) - sqrt(p))^2
//   f == 4   : (0.5 + 0.5*obj)*(obj - p)^2     (obj cells weight 1, noobj 0.5)
//   f >= 5   : obj*(onehot(label)[f-5] - p)^2
__device__ __forceinline__ float elem_loss(unsigned e, float p, const float* sTab) {
    unsigned lb   = e / CELLSZ;
    unsigned idx  = e - lb * CELLSZ;
    unsigned cell = idx / NFEAT;
    int f = (int)(idx - cell * NFEAT);
    const float* tb = &sTab[(lb * NCELL + cell) * 6];
    float obj = tb[0];
    if (f >= 5) {
        float t = (tb[5] == (float)(f - 5)) ? 1.f : 0.f;
        float d = t - p;
        return obj * d * d;
    }
    if (f == 4) {
        float d = obj - p;
        return (0.5f + 0.5f * obj) * d * d;
    }
    if (f < 2) {
        float d = (f == 0 ? tb[1] : tb[2]) - p;
        return 5.f * obj * d * d;
    }
    float d = (f == 2 ? tb[3] : tb[4]) - sqrtf(p);
    return 5.f * obj * d * d;
}

__global__ __launch_bounds__(256) void yolo_main(
    const float* __restrict__ pred, const float* __restrict__ bbox,
    float* __restrict__ partial, int B, int nbox)
{
    __shared__ float sRaw[BPB * MAXBOX * 5];
    __shared__ int   sCellIdx[BPB * MAXBOX];
    __shared__ float sBox[BPB * MAXBOX * 5];
    __shared__ float sTab[BPB * NCELL * 6];   // obj, xo, yo, sqrt(w), sqrt(h), label
    __shared__ float sRed[4];

    const int tid = threadIdx.x;
    const long long b0 = (long long)blockIdx.x * BPB;
    const int nb = min(BPB, B - (int)b0);

    // 1) stage raw bboxes (coalesced)
    const int nraw = nb * nbox * 5;
    for (int i = tid; i < nraw; i += 256)
        sRaw[i] = bbox[b0 * nbox * 5 + i];
    __syncthreads();

    // 2) per-box derived values (matches reference float32 op order)
    if (tid < nb * nbox) {
        const float* bx = &sRaw[tid * 5];
        float x1 = bx[0] / 448.f, y1 = bx[1] / 448.f;
        float x2 = bx[2] / 448.f, y2 = bx[3] / 448.f;
        float lab = bx[4];
        float xc = (x1 + x2) * 0.5f, yc = (y1 + y2) * 0.5f;
        float w  = x2 - x1,          h  = y2 - y1;
        float xs = xc * (float)GRIDS, ys = yc * (float)GRIDS;
        float xgf = floorf(xs), ygf = floorf(ys);
        sCellIdx[tid] = (int)ygf * GRIDS + (int)xgf;
        float* e = &sBox[tid * 5];
        e[0] = xs - xgf; e[1] = ys - ygf;
        e[2] = sqrtf(w); e[3] = sqrtf(h);
        e[4] = lab;
    }
    __syncthreads();

    // 3) cell table: first box (lowest j) claiming a cell wins (first-write-wins)
    for (int t = tid; t < nb * NCELL; t += 256) {
        int lb = t / NCELL, c = t - lb * NCELL;
        float obj = 0.f, xo = 0.f, yo = 0.f, sw = 0.f, sh = 0.f, lab = -1.f;
        for (int j = 0; j < nbox; ++j) {
            if (sCellIdx[lb * nbox + j] == c) {
                const float* e = &sBox[(lb * nbox + j) * 5];
                obj = 1.f; xo = e[0]; yo = e[1]; sw = e[2]; sh = e[3]; lab = e[4];
                break;
            }
        }
        float* o = &sTab[t * 6];
        o[0] = obj; o[1] = xo; o[2] = yo; o[3] = sw; o[4] = sh; o[5] = lab;
    }
    __syncthreads();

    // 4) main loop: float4 over this block's pred slab
    const int limit = nb * CELLSZ;
    const int nvec  = limit >> 2;
    const float*  pb = pred + b0 * CELLSZ;
    const float4* p4 = (const float4*)pb;
    float acc = 0.f;
    for (int i = tid; i < nvec; i += 256) {
        float4 v = p4[i];
        float pv[4] = {v.x, v.y, v.z, v.w};
        unsigned e0 = (unsigned)i << 2;
        #pragma unroll
        for (int k = 0; k < 4; ++k)
            acc += elem_loss(e0 + k, pv[k], sTab);
    }
    // scalar tail (only if limit % 4 != 0, i.e. partial last block)
    for (int e = (nvec << 2) + tid; e < limit; e += 256)
        acc += elem_loss((unsigned)e, pb[e], sTab);

    // 5) deterministic block reduction
    for (int off = 32; off; off >>= 1)
        acc += __shfl_down(acc, off, 64);
    if ((tid & 63) == 0) sRed[tid >> 6] = acc;
    __syncthreads();
    if (tid == 0)
        partial[blockIdx.x] = sRed[0] + sRed[1] + sRed[2] + sRed[3];
}

__global__ __launch_bounds__(256) void yolo_reduce(
    const float* __restrict__ partial, int n, float* __restrict__ out, int B)
{
    __shared__ double s[256];
    double a = 0.0;
    for (int i = threadIdx.x; i < n; i += 256) a += (double)partial[i];
    s[threadIdx.x] = a;
    __syncthreads();
    for (int str = 128; str; str >>= 1) {
        if (threadIdx.x < str) s[threadIdx.x] += s[threadIdx.x + str];
        __syncthreads();
    }
    if (threadIdx.x == 0) out[0] = (float)(s[0] / (double)B);
}

extern "C" void kernel_launch(void* const* d_in, const int* in_sizes, int n_in,
                              void* d_out, int out_size, void* d_ws, size_t ws_size,
                              hipStream_t stream) {
    const float* pred = (const float*)d_in[0];
    const float* bbox = (const float*)d_in[1];
    int B = in_sizes[0] / CELLSZ;
    int nbox = in_sizes[1] / (B * 5);
    if (nbox > MAXBOX) nbox = MAXBOX;
    float* out = (float*)d_out;
    float* partial = (float*)d_ws;

    int nblocks = (B + BPB - 1) / BPB;
    yolo_main<<<nblocks, 256, 0, stream>>>(pred, bbox, partial, B, nbox);
    yolo_reduce<<<1, 256, 0, stream>>>(partial, nblocks, out, B);
}

// Round 2
// 33.128 us; speedup vs baseline: 1.2035x; 1.2035x over previous
//
#include <hip/hip_runtime.h>

#define GRIDS 7
#define NCELL 49
#define NFEAT 25
#define CELLSZ 1225   // 49*25 floats per batch
#define BPB 8         // batches per block (8*4900 bytes => float4-aligned per block)
#define MAXBOX 16
#define ROW 6         // sTab row: [obj, lab_bits, xo, yo, sqrt(w), sqrt(h)]

// Branchless per-element loss.
//   f in [0,2): 5*obj*((xo|yo) - p)^2
//   f in [2,4): 5*obj*(sqrt(w|h) - sqrt(p))^2
//   f == 4   : (0.5 + 0.5*obj)*(obj - p)^2
//   f >= 5   : obj*(onehot(label)[f-5] - p)^2
// Row index in sTab is lb*49+cell == e/25 (global cell), so one magic-div.
__device__ __forceinline__ float elem_loss(unsigned e, float p, const float* sTab) {
    unsigned cg = (e * 20972u) >> 19;     // e / 25, exact for e < 43690
    unsigned f  = e - cg * 25u;           // feature index 0..24
    const float* row = sTab + cg * ROW;
    float obj  = row[0];
    int   lab  = __float_as_int(row[1]);
    float g    = row[2 + (f & 3u)];       // xo|yo|sw|sh for f<4 (garbage else, masked)
    float tcls = (lab == (int)f - 5) ? 1.f : 0.f;
    bool is_cls = f >= 5u;
    bool is_c   = f == 4u;
    bool is_sq  = (f - 2u) < 2u;          // f==2 || f==3
    float tgt = is_cls ? tcls : (is_c ? obj : g);
    float wgt = is_cls ? obj  : (is_c ? fmaf(obj, 0.5f, 0.5f) : 5.f * obj);
    float q   = is_sq ? sqrtf(p) : p;
    float d   = tgt - q;
    return (wgt * d) * d;
}

__global__ __launch_bounds__(256) void yolo_main(
    const float* __restrict__ pred, const float* __restrict__ bbox,
    float* __restrict__ partial, int B, int nbox)
{
    __shared__ float sRaw[BPB * MAXBOX * 5];
    __shared__ int   sCellIdx[BPB * MAXBOX];
    __shared__ float sBox[BPB * MAXBOX * 5];
    __shared__ float sTab[BPB * NCELL * ROW];
    __shared__ float sRed[4];

    const int tid = threadIdx.x;
    const long long b0 = (long long)blockIdx.x * BPB;
    const int nb = min(BPB, B - (int)b0);

    // 1) stage raw bboxes (coalesced)
    const int nraw = nb * nbox * 5;
    for (int i = tid; i < nraw; i += 256)
        sRaw[i] = bbox[b0 * nbox * 5 + i];
    __syncthreads();

    // 2) per-box derived values (matches reference float32 op order)
    if (tid < nb * nbox) {
        const float* bx = &sRaw[tid * 5];
        float x1 = bx[0] / 448.f, y1 = bx[1] / 448.f;
        float x2 = bx[2] / 448.f, y2 = bx[3] / 448.f;
        float xc = (x1 + x2) * 0.5f, yc = (y1 + y2) * 0.5f;
        float w  = x2 - x1,          h  = y2 - y1;
        float xs = xc * (float)GRIDS, ys = yc * (float)GRIDS;
        float xgf = floorf(xs), ygf = floorf(ys);
        sCellIdx[tid] = (int)ygf * GRIDS + (int)xgf;
        float* e = &sBox[tid * 5];
        e[0] = xs - xgf; e[1] = ys - ygf;
        e[2] = sqrtf(w); e[3] = sqrtf(h);
        e[4] = bx[4];
    }
    __syncthreads();

    // 3) cell table: first box (lowest j) claiming a cell wins
    for (int t = tid; t < nb * NCELL; t += 256) {
        int lb = t / NCELL, c = t - lb * NCELL;
        float obj = 0.f, xo = 0.f, yo = 0.f, sw = 0.f, sh = 0.f;
        int lab = -1;
        for (int j = 0; j < nbox; ++j) {
            if (sCellIdx[lb * nbox + j] == c) {
                const float* e = &sBox[(lb * nbox + j) * 5];
                obj = 1.f; xo = e[0]; yo = e[1]; sw = e[2]; sh = e[3];
                lab = (int)e[4];
                break;
            }
        }
        float* o = &sTab[t * ROW];
        o[0] = obj; o[1] = __int_as_float(lab);
        o[2] = xo; o[3] = yo; o[4] = sw; o[5] = sh;
    }
    __syncthreads();

    // 4) main loop: float4 over this block's pred slab, 2 loads in flight
    const int limit = nb * CELLSZ;
    const int nvec  = limit >> 2;          // 2450 for full blocks
    const float*  pb = pred + b0 * CELLSZ;
    const float4* p4 = (const float4*)pb;
    float acc = 0.f;
    int i = tid;
    for (; i + 256 < nvec; i += 512) {
        float4 a = p4[i];
        float4 b = p4[i + 256];
        unsigned ea = (unsigned)i << 2;
        unsigned eb = (unsigned)(i + 256) << 2;
        acc += elem_loss(ea,     a.x, sTab);
        acc += elem_loss(ea + 1, a.y, sTab);
        acc += elem_loss(ea + 2, a.z, sTab);
        acc += elem_loss(ea + 3, a.w, sTab);
        acc += elem_loss(eb,     b.x, sTab);
        acc += elem_loss(eb + 1, b.y, sTab);
        acc += elem_loss(eb + 2, b.z, sTab);
        acc += elem_loss(eb + 3, b.w, sTab);
    }
    if (i < nvec) {
        float4 a = p4[i];
        unsigned ea = (unsigned)i << 2;
        acc += elem_loss(ea,     a.x, sTab);
        acc += elem_loss(ea + 1, a.y, sTab);
        acc += elem_loss(ea + 2, a.z, sTab);
        acc += elem_loss(ea + 3, a.w, sTab);
    }
    // scalar tail (only for a partial last block)
    for (int e = (nvec << 2) + tid; e < limit; e += 256)
        acc += elem_loss((unsigned)e, pb[e], sTab);

    // 5) deterministic block reduction
    for (int off = 32; off; off >>= 1)
        acc += __shfl_down(acc, off, 64);
    if ((tid & 63) == 0) sRed[tid >> 6] = acc;
    __syncthreads();
    if (tid == 0)
        partial[blockIdx.x] = sRed[0] + sRed[1] + sRed[2] + sRed[3];
}

__global__ __launch_bounds__(256) void yolo_reduce(
    const float* __restrict__ partial, int n, float* __restrict__ out, int B)
{
    __shared__ double s[256];
    double a = 0.0;
    for (int i = threadIdx.x; i < n; i += 256) a += (double)partial[i];
    s[threadIdx.x] = a;
    __syncthreads();
    for (int str = 128; str; str >>= 1) {
        if (threadIdx.x < str) s[threadIdx.x] += s[threadIdx.x + str];
        __syncthreads();
    }
    if (threadIdx.x == 0) out[0] = (float)(s[0] / (double)B);
}

extern "C" void kernel_launch(void* const* d_in, const int* in_sizes, int n_in,
                              void* d_out, int out_size, void* d_ws, size_t ws_size,
                              hipStream_t stream) {
    const float* pred = (const float*)d_in[0];
    const float* bbox = (const float*)d_in[1];
    int B = in_sizes[0] / CELLSZ;
    int nbox = in_sizes[1] / (B * 5);
    if (nbox > MAXBOX) nbox = MAXBOX;
    float* out = (float*)d_out;
    float* partial = (float*)d_ws;

    int nblocks = (B + BPB - 1) / BPB;
    yolo_main<<<nblocks, 256, 0, stream>>>(pred, bbox, partial, B, nbox);
    yolo_reduce<<<1, 256, 0, stream>>>(partial, nblocks, out, B);
}